// Round 8
// baseline (968.863 us; speedup 1.0000x reference)
//
#include <hip/hip_runtime.h>

// Entropic Sinkhorn EMD, B=2, N=4096, D=3, EPS=0.1, 20 iters.
// Round-14: CHUNK-GRANULAR pipelined consumption. Round-13 bisect results:
// (1) two-level counters correct (absmax 0.0) -> round-12 bug was packed
// math; (2) FETCH dropped 17.1->7.2MB as predicted but time ROSE 662->744us
// -> poll-contention theory FALSIFIED; stall is latency/serialization of the
// whole-phase barrier (max block skew + store drain + counter hops + wake +
// first-miss, in series, every phase).
// Fix: the dependency is per-chunk, not per-phase. 16 per-chunk counters per
// (cloud,b) chain (group g = 32 blocks owning dual rows [g*256,(g+1)*256));
// producer incs its chunk counter after vmcnt(0) (single hop, promotion
// removed). Consumers drain-loop per wave: batched poll (lanes 0-15) ->
// ballot -> process all ready chunks (popped in PAIRS for 4 loads in
// flight), sleep only when nothing is processable. Producer skew overlaps
// with consumer compute. Per-pair math byte-identical to round-10/13.

#define N     4096
#define NT    256
#define RPB   8      // rows per block -> grid (512, 2) = 1024 blocks = 4/CU
#define NGRP  16     // chunks == producer groups per (cloud,b); 32 blocks each
#define GRPSZ 32
#define CSTR  32     // counter stride in u32 (128 B, one line per counter)

constexpr float EPS_F  = 0.1f;
constexpr float SHIFT  = 60.0f;
constexpr float LOG_A  = -8.317766166719343f;   // -log(4096)
constexpr float C10L   = 14.426950408889634f;   // 10*log2(e)
constexpr float C20L   = 28.853900817779268f;   // 20*log2(e)
constexpr float SHIFTL = 86.56170245333781f;    // SHIFT*log2(e)
constexpr float NLN2T  = -0.06931471805599453f; // -ln2/10
constexpr float LN2    = 0.6931471805599453f;

extern "C" __device__ float __ocml_native_exp2_f32(float);

__device__ __forceinline__ float fast_exp2(float x) {
#if __has_builtin(__builtin_amdgcn_exp2f)
    return __builtin_amdgcn_exp2f(x);
#else
    return __ocml_native_exp2_f32(x);
#endif
}

__device__ __forceinline__ float rfl(float x) {
    return __int_as_float(__builtin_amdgcn_readfirstlane(__float_as_int(x)));
}

// Agent-scope (LLC-performed) store: visible to cross-XCD consumers' L2
// misses without any cache maintenance.
__device__ __forceinline__ void llc_storef(float* p, float v) {
    __hip_atomic_store(p, v, __ATOMIC_RELAXED, __HIP_MEMORY_SCOPE_AGENT);
}

// Pack {x,y,z, SHIFTL - 10L|p|^2} (CONSTANT); zero counters, gRing version 0
// (Sinkhorn g=0 init), and out. Other ring versions untouched (first-touch-
// after-write keeps cached consumer reads coherent).
__global__ __launch_bounds__(256) void prep_kernel(
    const float* __restrict__ gen, const float* __restrict__ gt,
    float4* __restrict__ genPack, float4* __restrict__ gtPack,
    float* __restrict__ gRing0, unsigned* __restrict__ cnt,
    float* __restrict__ out)
{
    int t = blockIdx.x * 256 + threadIdx.x;   // 0 .. 16383
    if (t < 8192) cnt[t] = 0u;                // 2048 u32 used + pad
    if (t < 8192) gRing0[t] = 0.0f;           // g*C10L = 0 initial state
    int cloud = t >> 13;
    int idx   = t & 8191;                     // b*N + j
    const float* src = cloud ? gt : gen;
    float x = src[idx * 3 + 0];
    float y = src[idx * 3 + 1];
    float z = src[idx * 3 + 2];
    float nb = -C10L * fmaf(z, z, fmaf(y, y, x * x));   // -10L|p|^2
    (cloud ? gtPack : genPack)[idx] = make_float4(x, y, z, SHIFTL + nb);
    if (t == 0) out[0] = 0.0f;
}

// One half-sweep with chunk-granular drain. Per-pair math identical to the
// verified round-10/13 kernels; only consumption ORDER is data-driven.
__device__ __forceinline__ void sweep_phase(
    const float4* __restrict__ cp,   // column pack (constant, cached)
    const float*  __restrict__ h2c,  // column duals, ring version (cached)
    float*        __restrict__ h2o,  // own-row dual out (+rowBase, LLC store)
    const unsigned* __restrict__ cw, // 16 chunk counters to consume
    unsigned*       __restrict__ ci, // own chunk counter to bump
    unsigned target,
    const float (&X)[RPB], const float (&Y)[RPB],
    const float (&Z)[RPB], const float (&S)[RPB],
    int tid, float (&sred)[RPB][4])
{
    const int lane = tid & 63;
    float acc[RPB];
    #pragma unroll
    for (int r = 0; r < RPB; ++r) acc[r] = 0.0f;

    unsigned done = 0u;
    while (done != 0xffffu) {
        unsigned c = 0xffffffffu;
        if (lane < NGRP && !((done >> lane) & 1u))
            c = __hip_atomic_load(cw + lane * CSTR, __ATOMIC_RELAXED,
                                  __HIP_MEMORY_SCOPE_AGENT);
        unsigned long long bl = __ballot(c >= target);
        unsigned todo = ((unsigned)bl & 0xffffu) & ~done;
        if (todo == 0u) { __builtin_amdgcn_s_sleep(1); continue; }
        done |= todo;
        asm volatile("" ::: "memory");   // ring loads stay below the poll
        while (todo) {
            int k1 = __builtin_ctz(todo); todo &= todo - 1u;
            int j1 = (k1 << 8) + tid;
            float4 p1 = cp[j1]; float h1 = h2c[j1];
            if (todo) {
                int k2 = __builtin_ctz(todo); todo &= todo - 1u;
                int j2 = (k2 << 8) + tid;
                float4 p2 = cp[j2]; float h2v = h2c[j2];
                float w1 = p1.w + h1, w2 = p2.w + h2v;
                #pragma unroll
                for (int r = 0; r < RPB; ++r) {
                    float ta = fmaf(Z[r], p1.z, w1);
                    ta = fmaf(Y[r], p1.y, ta);
                    ta = fmaf(X[r], p1.x, ta);
                    float tb = fmaf(Z[r], p2.z, w2);
                    tb = fmaf(Y[r], p2.y, tb);
                    tb = fmaf(X[r], p2.x, tb);
                    acc[r] += fast_exp2(ta + S[r]);
                    acc[r] += fast_exp2(tb + S[r]);
                }
            } else {
                float w1 = p1.w + h1;
                #pragma unroll
                for (int r = 0; r < RPB; ++r) {
                    float ta = fmaf(Z[r], p1.z, w1);
                    ta = fmaf(Y[r], p1.y, ta);
                    ta = fmaf(X[r], p1.x, ta);
                    acc[r] += fast_exp2(ta + S[r]);
                }
            }
        }
    }

    #pragma unroll
    for (int r = 0; r < RPB; ++r) {
        float a = acc[r];
        a += __shfl_xor(a, 32);
        a += __shfl_xor(a, 16);
        a += __shfl_xor(a, 8);
        a += __shfl_xor(a, 4);
        a += __shfl_xor(a, 2);
        a += __shfl_xor(a, 1);
        acc[r] = a;
    }
    const int wave = tid >> 6;
    if (lane == 0) {
        #pragma unroll
        for (int r = 0; r < RPB; ++r) sred[r][wave] = acc[r];
    }
    __syncthreads();
    if (tid < RPB) {
        float s = (sred[tid][0] + sred[tid][1]) + (sred[tid][2] + sred[tid][3]);
        float dual = EPS_F * (LOG_A + SHIFT - log2f(s) * LN2);
        llc_storef(h2o + tid, dual * C10L);
        // order: dual stores performed at LLC before the arrival inc
        asm volatile("s_waitcnt vmcnt(0)" ::: "memory");
    }
    __syncthreads();
    if (tid == 0)
        __hip_atomic_fetch_add(ci, 1u, __ATOMIC_RELAXED,
                               __HIP_MEMORY_SCOPE_AGENT);
}

__global__ __launch_bounds__(NT, 4) void sinkhorn_main(
    const float4* __restrict__ packGen, const float4* __restrict__ packGt,
    float* __restrict__ fRing,   // 20 versions x [2][N]
    float* __restrict__ gRing,   // 21 versions x [2][N]
    unsigned* __restrict__ cnt, float* __restrict__ out)
{
    const int b       = blockIdx.y;
    const int tid     = threadIdx.x;
    const int rowBase = blockIdx.x * RPB;
    const int grp     = blockIdx.x >> 5;     // 0..15, 32 blocks each
    __shared__ float sred[RPB][4];

    const size_t bN = (size_t)b * N;

    const float4* rpG = packGen + bN + rowBase;
    const float4* rpT = packGt  + bN + rowBase;

    float XG[RPB], YG[RPB], ZG[RPB], SG[RPB];
    float XT[RPB], YT[RPB], ZT[RPB], ST[RPB];
    #pragma unroll
    for (int r = 0; r < RPB; ++r) {
        float4 q = rpG[r];
        XG[r] = rfl(q.x * C20L);
        YG[r] = rfl(q.y * C20L);
        ZG[r] = rfl(q.z * C20L);
        SG[r] = rfl(q.w - SHIFTL);           // -10L|p_i|^2
    }
    #pragma unroll
    for (int r = 0; r < RPB; ++r) {
        float4 q = rpT[r];
        XT[r] = rfl(q.x * C20L);
        YT[r] = rfl(q.y * C20L);
        ZT[r] = rfl(q.z * C20L);
        ST[r] = rfl(q.w - SHIFTL);
    }

    const float4* cpG = packGen + bN;
    const float4* cpT = packGt  + bN;

    unsigned* cntF = cnt + (size_t)(b * 2 + 0) * NGRP * CSTR;
    unsigned* cntG = cnt + (size_t)(b * 2 + 1) * NGRP * CSTR;

    #pragma unroll 1
    for (unsigned t = 0; t < 20; ++t) {
        // f-update: rows=gen, cols=gt; reads gRing[t], writes fRing[t]
        sweep_phase(cpT,
                    gRing + (size_t)t * 2 * N + bN,
                    fRing + (size_t)t * 2 * N + bN + rowBase,
                    cntG, cntF + grp * CSTR, GRPSZ * t,
                    XG, YG, ZG, SG, tid, sred);
        // g-update: rows=gt, cols=gen; reads fRing[t], writes gRing[t+1]
        sweep_phase(cpG,
                    fRing + (size_t)t * 2 * N + bN,
                    gRing + (size_t)(t + 1) * 2 * N + bN + rowBase,
                    cntF, cntG + grp * CSTR, GRPSZ * (t + 1),
                    XT, YT, ZT, ST, tid, sred);
    }

    // ---- loss: += 0.5 * sum_ij exp((f_i + g_j - C_ij)/EPS) * C_ij
    // (chunk-granular drain on the final g chain as well)
    {
        const float* fFin = fRing + (size_t)19 * 2 * N + bN;
        const float* gFin = gRing + (size_t)20 * 2 * N + bN;
        const int lane = tid & 63;

        float Ax[RPB], Ay[RPB], Az[RPB], Ri[RPB], F2[RPB];
        #pragma unroll
        for (int r = 0; r < RPB; ++r) {
            float4 q = rpG[r];
            Ax[r] = rfl(q.x * -2.0f);
            Ay[r] = rfl(q.y * -2.0f);
            Az[r] = rfl(q.z * -2.0f);
            Ri[r] = rfl((q.w - SHIFTL) * NLN2T);      // |p_i|^2
            F2[r] = rfl(fFin[rowBase + r]);           // f_i*C10L (own rows)
        }

        const unsigned target = GRPSZ * 20u;
        float acc = 0.0f;
        unsigned done = 0u;
        while (done != 0xffffu) {
            unsigned c = 0xffffffffu;
            if (lane < NGRP && !((done >> lane) & 1u))
                c = __hip_atomic_load(cntG + lane * CSTR, __ATOMIC_RELAXED,
                                      __HIP_MEMORY_SCOPE_AGENT);
            unsigned long long bl = __ballot(c >= target);
            unsigned todo = ((unsigned)bl & 0xffffu) & ~done;
            if (todo == 0u) { __builtin_amdgcn_s_sleep(1); continue; }
            done |= todo;
            asm volatile("" ::: "memory");
            while (todo) {
                int k = __builtin_ctz(todo); todo &= todo - 1u;
                int j = (k << 8) + tid;
                float4 p = cpT[j];
                float G2 = gFin[j];                      // g_j * C10L
                float rj = (p.w - SHIFTL) * NLN2T;       // |p_j|^2
                #pragma unroll
                for (int r = 0; r < RPB; ++r) {
                    float cc = rj + Ri[r];
                    cc = fmaf(Az[r], p.z, cc);
                    cc = fmaf(Ay[r], p.y, cc);
                    cc = fmaf(Ax[r], p.x, cc);
                    float arg = fmaf(cc, -C10L, G2 + F2[r]);
                    acc = fmaf(fast_exp2(arg), cc, acc);
                }
            }
        }

        acc += __shfl_xor(acc, 32);
        acc += __shfl_xor(acc, 16);
        acc += __shfl_xor(acc, 8);
        acc += __shfl_xor(acc, 4);
        acc += __shfl_xor(acc, 2);
        acc += __shfl_xor(acc, 1);
        const int wave = tid >> 6;
        if (lane == 0) sred[0][wave] = acc;
        __syncthreads();
        if (tid == 0) {
            float t2 = (sred[0][0] + sred[0][1]) + (sred[0][2] + sred[0][3]);
            atomicAdd(out, t2 * 0.5f);
        }
    }
}

extern "C" void kernel_launch(void* const* d_in, const int* in_sizes, int n_in,
                              void* d_out, int out_size, void* d_ws, size_t ws_size,
                              hipStream_t stream) {
    const float* gen = (const float*)d_in[0];
    const float* gt  = (const float*)d_in[1];
    float* out = (float*)d_out;

    char* ws = (char*)d_ws;
    float4*   genPack = (float4*)ws;                       // [0,   128K)
    float4*   gtPack  = (float4*)(ws + 128 * 1024);        // [128K,256K)
    unsigned* cnt     = (unsigned*)(ws + 256 * 1024);      // [256K,288K) 8192 u32
    float*    fRing   = (float*)(ws + 288 * 1024);         // [288K,928K) 20x32KB
    float*    gRing   = (float*)(ws + 928 * 1024);         // [928K,1600K) 21x32KB

    prep_kernel<<<dim3(16384 / 256), 256, 0, stream>>>(
        gen, gt, genPack, gtPack, gRing, cnt, out);

    sinkhorn_main<<<dim3(N / RPB, 2), NT, 0, stream>>>(
        genPack, gtPack, fRing, gRing, cnt, out);
}